// Round 4
// baseline (687.822 us; speedup 1.0000x reference)
//
#include <hip/hip_runtime.h>
#include <hip/hip_bf16.h>
#include <math.h>

#define SS 196
#define DD 768

__device__ __forceinline__ float b2f(ushort u){
  union { unsigned int i; float f; } v; v.i = ((unsigned int)u) << 16; return v.f;
}
__device__ __forceinline__ bool bfmode(const void* lnw){
  return ((const ushort*)lnw)[0] != 0;   // ln_w[0]==1.0: fp32 low half 0x0000, bf16 0x3F80
}
__device__ __forceinline__ float ldx(const void* p, size_t i, bool bf){
  return bf ? b2f(((const ushort*)p)[i]) : ((const float*)p)[i];
}
__device__ __forceinline__ float gelu_f(float x){
  return 0.5f * x * (1.0f + erff(x * 0.70710678118654752f));
}
__device__ __forceinline__ float wredsum(float v){
  #pragma unroll
  for(int o=32;o;o>>=1) v += __shfl_xor(v,o,64);
  return v;
}
__device__ __forceinline__ float wredmax(float v){
  #pragma unroll
  for(int o=32;o;o>>=1) v = fmaxf(v, __shfl_xor(v,o,64));
  return v;
}

__global__ __launch_bounds__(256) void k_qh(const void* __restrict__ q,
                                            const void* __restrict__ wq,
                                            const void* __restrict__ bq,
                                            const void* __restrict__ flagp,
                                            float* __restrict__ qh){
  bool bf = bfmode(flagp);
  int wv = threadIdx.x >> 6, lane = threadIdx.x & 63;
  int c = blockIdx.x * 4 + wv;
  float acc = 0.f;
  #pragma unroll
  for(int i=0;i<12;i++){ int d = lane + 64*i; acc += ldx(q,d,bf) * ldx(wq,(size_t)c*DD+d,bf); }
  acc = wredsum(acc);
  if(lane==0) qh[c] = acc + ldx(bq,c,bf);
}

__global__ __launch_bounds__(256) void k_wkeff(const void* __restrict__ wproj,
                                               const float* __restrict__ qh,
                                               const void* __restrict__ lnw,
                                               const void* __restrict__ objw,
                                               float* __restrict__ wkraw,
                                               float* __restrict__ wf){
  bool bf = bfmode(lnw);
  int idx = blockIdx.x*256 + threadIdx.x;
  int h = idx / DD, d = idx - h*DD;
  size_t base = ((size_t)(DD + h*192))*DD + d;
  const float* qp = qh + h*192;
  float acc = 0.f;
  #pragma unroll 8
  for(int j=0;j<192;j++) acc += qp[j] * ldx(wproj, base + (size_t)j*DD, bf);
  wkraw[idx] = acc;
  float w = ldx(lnw,d,bf);
  wf[idx] = w * acc;
  if(h==0) wf[4*DD + d] = w * ldx(objw,d,bf);
}

__global__ __launch_bounds__(256) void k_consts(const float* __restrict__ wf,
                                                const float* __restrict__ wkraw,
                                                const void* __restrict__ lnb,
                                                const void* __restrict__ objw,
                                                const void* __restrict__ flagp,
                                                float* __restrict__ s12){
  bool bf = bfmode(flagp);
  int wv = threadIdx.x >> 6, lane = threadIdx.x & 63;
  for(int r = wv; r < 10; r += 4){
    float acc = 0.f;
    #pragma unroll
    for(int i=0;i<12;i++){
      int d = lane + 64*i;
      if(r < 5)      acc += wf[r*DD + d];
      else if(r < 9) acc += ldx(lnb,d,bf) * wkraw[(r-5)*DD + d];
      else           acc += ldx(lnb,d,bf) * ldx(objw,d,bf);
    }
    acc = wredsum(acc);
    if(lane==0) s12[r] = acc;
  }
}

__global__ __launch_bounds__(256) void k_pass1(const void* __restrict__ tok,
                                               const float* __restrict__ wf,
                                               const float* __restrict__ s12,
                                               const void* __restrict__ objb,
                                               const void* __restrict__ flagp,
                                               float* __restrict__ scores,
                                               float* __restrict__ objv,
                                               float* __restrict__ meanv,
                                               float* __restrict__ rstdv){
  __shared__ __align__(16) float swf[5*DD];
  __shared__ float ss12[10];
  for(int i=threadIdx.x;i<5*DD;i+=256) swf[i]=wf[i];
  if(threadIdx.x<10) ss12[threadIdx.x]=s12[threadIdx.x];
  __syncthreads();
  bool bf = bfmode(flagp);
  int wv = threadIdx.x >> 6, lane = threadIdx.x & 63;
  for(int it=0; it<4; it++){
    int tkn = blockIdx.x*16 + wv*4 + it;
    int f = tkn / SS, s = tkn - f*SS;
    float a0=0,a1=0,a2=0,a3=0,a4=0,sm=0,sq=0;
    if(bf){
      const ushort* x = (const ushort*)tok + (size_t)tkn * DD;
      #pragma unroll
      for(int i=0;i<6;i++){
        int d = 2*lane + 128*i;
        ushort2 u = *(const ushort2*)(x + d);
        float x0=b2f(u.x), x1=b2f(u.y);
        sm += x0 + x1; sq += x0*x0 + x1*x1;
        float2 w;
        w = *(const float2*)&swf[0*DD+d]; a0 += x0*w.x + x1*w.y;
        w = *(const float2*)&swf[1*DD+d]; a1 += x0*w.x + x1*w.y;
        w = *(const float2*)&swf[2*DD+d]; a2 += x0*w.x + x1*w.y;
        w = *(const float2*)&swf[3*DD+d]; a3 += x0*w.x + x1*w.y;
        w = *(const float2*)&swf[4*DD+d]; a4 += x0*w.x + x1*w.y;
      }
    } else {
      const float* x = (const float*)tok + (size_t)tkn * DD;
      #pragma unroll
      for(int i=0;i<3;i++){
        int d = 4*lane + 256*i;
        float4 u = *(const float4*)(x + d);
        sm += u.x+u.y+u.z+u.w;
        sq += u.x*u.x+u.y*u.y+u.z*u.z+u.w*u.w;
        float4 w;
        w = *(const float4*)&swf[0*DD+d]; a0 += u.x*w.x+u.y*w.y+u.z*w.z+u.w*w.w;
        w = *(const float4*)&swf[1*DD+d]; a1 += u.x*w.x+u.y*w.y+u.z*w.z+u.w*w.w;
        w = *(const float4*)&swf[2*DD+d]; a2 += u.x*w.x+u.y*w.y+u.z*w.z+u.w*w.w;
        w = *(const float4*)&swf[3*DD+d]; a3 += u.x*w.x+u.y*w.y+u.z*w.z+u.w*w.w;
        w = *(const float4*)&swf[4*DD+d]; a4 += u.x*w.x+u.y*w.y+u.z*w.z+u.w*w.w;
      }
    }
    sm=wredsum(sm); sq=wredsum(sq);
    a0=wredsum(a0); a1=wredsum(a1); a2=wredsum(a2); a3=wredsum(a3); a4=wredsum(a4);
    if(lane==0){
      const float invD = 1.0f/768.0f;
      float m = sm*invD;
      float var = sq*invD - m*m;
      float rstd = rsqrtf(var + 1e-5f);
      meanv[tkn]=m; rstdv[tkn]=rstd;
      const float sc = 0.07216878364870322f;
      scores[(f*4+0)*SS+s] = (rstd*(a0 - m*ss12[0]) + ss12[5]) * sc;
      scores[(f*4+1)*SS+s] = (rstd*(a1 - m*ss12[1]) + ss12[6]) * sc;
      scores[(f*4+2)*SS+s] = (rstd*(a2 - m*ss12[2]) + ss12[7]) * sc;
      scores[(f*4+3)*SS+s] = (rstd*(a3 - m*ss12[3]) + ss12[8]) * sc;
      objv[tkn] = rstd*(a4 - m*ss12[4]) + ss12[9] + ldx(objb,0,bf);
    }
  }
}

__global__ __launch_bounds__(256) void k_soft(const float* __restrict__ rstdv,
                                              const float* __restrict__ meanv,
                                              float* __restrict__ scores,
                                              float* __restrict__ cterm){
  int f = blockIdx.x;
  int h = threadIdx.x >> 6, lane = threadIdx.x & 63;
  float* sc = scores + (size_t)(f*4+h)*SS;
  const float* rs = rstdv + f*SS;
  const float* mv = meanv + f*SS;
  float v[4]; float mx = -1e30f;
  #pragma unroll
  for(int j=0;j<4;j++){ int s=lane+64*j; v[j] = (s<SS)? sc[s] : -1e30f; mx=fmaxf(mx,v[j]); }
  mx = wredmax(mx);
  float e[4], sum=0.f;
  #pragma unroll
  for(int j=0;j<4;j++){ int s=lane+64*j; e[j] = (s<SS)? expf(v[j]-mx) : 0.f; sum += e[j]; }
  sum = wredsum(sum);
  float inv = 1.0f/sum;
  float cp = 0.f;
  #pragma unroll
  for(int j=0;j<4;j++){
    int s=lane+64*j;
    if(s<SS){ float r=rs[s]; float a=e[j]*inv*r; sc[s]=a; cp += a*mv[s]; }
  }
  cp = wredsum(cp);
  if(lane==0) cterm[f*4+h] = cp;
}

__global__ __launch_bounds__(256) void k_xbar(const void* __restrict__ tok,
                                              const float* __restrict__ aw,
                                              const float* __restrict__ cterm,
                                              const void* __restrict__ lnw,
                                              const void* __restrict__ lnb,
                                              float* __restrict__ xbar){
  bool bf = bfmode(lnw);
  int f = blockIdx.x;
  __shared__ float a4[SS*4];
  for(int i=threadIdx.x;i<SS*4;i+=256){ int s=i>>2, h=i&3; a4[i]=aw[(size_t)(f*4+h)*SS+s]; }
  __syncthreads();
  float acc[3][4] = {};
  if(bf){
    const ushort* tf = (const ushort*)tok + (size_t)f*SS*DD;
    for(int s=0;s<SS;s++){
      float w0=a4[s*4+0], w1=a4[s*4+1], w2=a4[s*4+2], w3=a4[s*4+3];
      #pragma unroll
      for(int j=0;j<3;j++){
        float x = b2f(tf[(size_t)s*DD + threadIdx.x + 256*j]);
        acc[j][0]+=w0*x; acc[j][1]+=w1*x; acc[j][2]+=w2*x; acc[j][3]+=w3*x;
      }
    }
  } else {
    const float* tf = (const float*)tok + (size_t)f*SS*DD;
    for(int s=0;s<SS;s++){
      float w0=a4[s*4+0], w1=a4[s*4+1], w2=a4[s*4+2], w3=a4[s*4+3];
      #pragma unroll
      for(int j=0;j<3;j++){
        float x = tf[(size_t)s*DD + threadIdx.x + 256*j];
        acc[j][0]+=w0*x; acc[j][1]+=w1*x; acc[j][2]+=w2*x; acc[j][3]+=w3*x;
      }
    }
  }
  float c0=cterm[f*4+0], c1=cterm[f*4+1], c2=cterm[f*4+2], c3=cterm[f*4+3];
  #pragma unroll
  for(int j=0;j<3;j++){
    int d = threadIdx.x + 256*j;
    float w=ldx(lnw,d,bf), b=ldx(lnb,d,bf);
    xbar[((size_t)(f*4+0))*DD+d] = w*(acc[j][0]-c0)+b;
    xbar[((size_t)(f*4+1))*DD+d] = w*(acc[j][1]-c1)+b;
    xbar[((size_t)(f*4+2))*DD+d] = w*(acc[j][2]-c2)+b;
    xbar[((size_t)(f*4+3))*DD+d] = w*(acc[j][3]-c3)+b;
  }
}

// ---- dot-product GEMM: C[256][N] = A[256][K] @ W[ROWOFF+n][K]^T + bias ----------
// One thread per output. Block = 4 rows x 64 cols; grid (N/64, 64).
// A-row address is wave-uniform (L1 broadcast); W rows stream via 16B loads.
// CTX=1: A row for output row m, col block n0 is xbar[(m*4 + n0/192)*768 + k].
template<int N, int K, int ACT, int CTX, int ROWOFF>
__global__ __launch_bounds__(256) void k_dgemm(const float* __restrict__ A,
                                               const void* __restrict__ W,
                                               const void* __restrict__ bias,
                                               const void* __restrict__ flagp,
                                               float* __restrict__ C){
  bool bf = bfmode(flagp);
  int tid = threadIdx.x;
  int m0 = blockIdx.y*4, n0 = blockIdx.x*64;
  int mi = tid >> 6;           // wave id = row within block (wave-uniform)
  int n  = n0 + (tid & 63);
  int h  = n0 / 192;           // 64-col tiles never straddle a 192 head block
  int m  = m0 + mi;
  const size_t arow = CTX ? ((size_t)(m*4 + h))*768 : (size_t)m*K;
  const float* ar = A + arow;
  float acc = 0.f;
  if(bf){
    const ushort* wr = (const ushort*)W + (size_t)(ROWOFF+n)*K;
    for(int k=0;k<K;k+=8){
      float4 a0 = *(const float4*)(ar+k);
      float4 a1 = *(const float4*)(ar+k+4);
      ushort4 w0 = *(const ushort4*)(wr+k);
      ushort4 w1 = *(const ushort4*)(wr+k+4);
      acc += a0.x*b2f(w0.x) + a0.y*b2f(w0.y) + a0.z*b2f(w0.z) + a0.w*b2f(w0.w)
           + a1.x*b2f(w1.x) + a1.y*b2f(w1.y) + a1.z*b2f(w1.z) + a1.w*b2f(w1.w);
    }
  } else {
    const float* wr = (const float*)W + (size_t)(ROWOFF+n)*K;
    for(int k=0;k<K;k+=8){
      float4 a0 = *(const float4*)(ar+k);
      float4 a1 = *(const float4*)(ar+k+4);
      float4 w0 = *(const float4*)(wr+k);
      float4 w1 = *(const float4*)(wr+k+4);
      acc += a0.x*w0.x + a0.y*w0.y + a0.z*w0.z + a0.w*w0.w
           + a1.x*w1.x + a1.y*w1.y + a1.z*w1.z + a1.w*w1.w;
    }
  }
  acc += ldx(bias, ROWOFF+n, bf);
  if(ACT) acc = gelu_f(acc);
  C[(size_t)m*N + n] = acc;
}

__global__ __launch_bounds__(256) void k_lnan(const float* __restrict__ X,
                                              const void* __restrict__ anw,
                                              const void* __restrict__ anb,
                                              const void* __restrict__ flagp,
                                              float* __restrict__ pl){
  bool bf = bfmode(flagp);
  int wv = threadIdx.x >> 6, lane = threadIdx.x & 63;
  int f = blockIdx.x*4 + wv;
  const float* x = X + (size_t)f*DD;
  float v[12]; float sm=0, sq=0;
  #pragma unroll
  for(int i=0;i<12;i++){ v[i]=x[lane+64*i]; sm+=v[i]; sq+=v[i]*v[i]; }
  sm=wredsum(sm); sq=wredsum(sq);
  float m = sm*(1.0f/768.0f);
  float rstd = rsqrtf(sq*(1.0f/768.0f) - m*m + 1e-5f);
  #pragma unroll
  for(int i=0;i<12;i++){
    int d = lane+64*i;
    pl[(size_t)f*1536 + d] = (v[i]-m)*rstd*ldx(anw,d,bf) + ldx(anb,d,bf);
  }
}

__global__ __launch_bounds__(256) void k_obj(const void* __restrict__ tok,
                                             const float* __restrict__ objv,
                                             const float* __restrict__ meanv,
                                             const float* __restrict__ rstdv,
                                             const void* __restrict__ temp,
                                             const void* __restrict__ lnw,
                                             const void* __restrict__ lnb,
                                             float* __restrict__ pl,
                                             float* __restrict__ cxy){
  bool bf = bfmode(lnw);
  int f = blockIdx.x;
  int tid = threadIdx.x;
  __shared__ float G[196];
  __shared__ float up[3136];
  __shared__ int   i0a[56], i1a[56];
  __shared__ float w0a[56], w1a[56];
  __shared__ float redm[4], reds[4], redx[4], redy[4];
  __shared__ int   sidx[9];
  __shared__ float rj[9], rmj[9];
  if(tid<196) G[tid] = objv[(size_t)f*SS + tid];
  if(tid<56){
    float src = fmaxf((tid+0.5f)*0.25f - 0.5f, 0.0f);
    int i0 = min((int)floorf(src), 13);
    i0a[tid]=i0; i1a[tid]=min(i0+1,13);
    float w1 = src - (float)i0;
    w1a[tid]=w1; w0a[tid]=1.0f-w1;
  }
  __syncthreads();
  float lmax = -1e30f;
  for(int i=tid;i<3136;i+=256){
    int u=i/56, v=i-u*56;
    float val = w0a[u]*(w0a[v]*G[i0a[u]*14+i0a[v]] + w1a[v]*G[i0a[u]*14+i1a[v]])
              + w1a[u]*(w0a[v]*G[i1a[u]*14+i0a[v]] + w1a[v]*G[i1a[u]*14+i1a[v]]);
    up[i]=val; lmax=fmaxf(lmax,val);
  }
  lmax = wredmax(lmax);
  if((tid&63)==0) redm[tid>>6]=lmax;
  __syncthreads();
  float mx = fmaxf(fmaxf(redm[0],redm[1]), fmaxf(redm[2],redm[3]));
  float t = fmaxf(ldx(temp,0,bf), 1.0f);
  float se=0, sx=0, sy=0;
  for(int i=tid;i<3136;i+=256){
    int u=i/56, v=i-u*56;
    float e = expf((up[i]-mx)*t);
    se += e;
    sx += e * ((v+0.5f)*(1.0f/56.0f));
    sy += e * ((u+0.5f)*(1.0f/56.0f));
  }
  se=wredsum(se); sx=wredsum(sx); sy=wredsum(sy);
  if((tid&63)==0){ reds[tid>>6]=se; redx[tid>>6]=sx; redy[tid>>6]=sy; }
  __syncthreads();
  se = reds[0]+reds[1]+reds[2]+reds[3];
  sx = redx[0]+redx[1]+redx[2]+redx[3];
  sy = redy[0]+redy[1]+redy[2]+redy[3];
  float cx0 = sx/se, cy0 = sy/se;
  if(tid==0){ cxy[f*2]=cx0; cxy[f*2+1]=cy0; }
  float vx = fminf(fmaxf(cx0*14.0f,0.0f),13.0f); int cxg=(int)vx;
  float vy = fminf(fmaxf(cy0*14.0f,0.0f),13.0f); int cyg=(int)vy;
  if(tid<9){
    int dy = tid/3 - 1, dx = tid%3 - 1;
    int gy = min(max(cyg+dy,0),13), gx = min(max(cxg+dx,0),13);
    int s = gy*14+gx;
    sidx[tid]=s;
    float r = rstdv[(size_t)f*SS+s];
    rj[tid]=r; rmj[tid]=r*meanv[(size_t)f*SS+s];
  }
  __syncthreads();
  float offc = 0.f;
  #pragma unroll
  for(int j=0;j<9;j++) offc += rmj[j];
  for(int d=tid; d<DD; d+=256){
    float acc = 0.f;
    #pragma unroll
    for(int j=0;j<9;j++) acc += rj[j]*ldx(tok, (size_t)f*SS*DD + (size_t)sidx[j]*DD + d, bf);
    pl[(size_t)f*1536 + DD + d] = ldx(lnw,d,bf)*((acc-offc)*(1.0f/9.0f)) + ldx(lnb,d,bf);
  }
}

__global__ __launch_bounds__(256) void k_final(const float* __restrict__ h2,
                                               const void* __restrict__ r3w,
                                               const void* __restrict__ r3b,
                                               const float* __restrict__ cxy,
                                               const void* __restrict__ tc1w,
                                               const void* __restrict__ tc1b,
                                               const void* __restrict__ tc2w,
                                               const void* __restrict__ tc2b,
                                               const void* __restrict__ fbw,
                                               const void* __restrict__ flagp,
                                               void* __restrict__ out){
  bool bf = bfmode(flagp);
  __shared__ float sxs[256], sys[256];
  __shared__ float t1[16*32*16];
  __shared__ float td[16*2*16];
  int f = threadIdx.x;
  float a0=0.f, a1=0.f;
  const float* hh = h2 + (size_t)f*128;
  for(int k=0;k<128;k++){ float x=hh[k]; a0 += x*ldx(r3w,k,bf); a1 += x*ldx(r3w,128+k,bf); }
  a0 += ldx(r3b,0,bf); a1 += ldx(r3b,1,bf);
  float cx1 = fminf(fmaxf(cxy[f*2]   + 0.3f*tanhf(a0), 0.f), 1.f);
  float cy1 = fminf(fmaxf(cxy[f*2+1] + 0.3f*tanhf(a1), 0.f), 1.f);
  sxs[f]=cx1; sys[f]=cy1;
  __syncthreads();
  for(int idx=f; idx<8192; idx+=256){
    int b = idx>>9, o = (idx>>4)&31, t = idx&15;
    float acc = ldx(tc1b,o,bf);
    #pragma unroll
    for(int k=0;k<5;k++){
      int tt = t + k - 2;
      if(tt>=0 && tt<16)
        acc += sxs[b*16+tt]*ldx(tc1w,o*10 + k,bf) + sys[b*16+tt]*ldx(tc1w,o*10 + 5 + k,bf);
    }
    t1[idx] = gelu_f(acc);
  }
  __syncthreads();
  for(int idx=f; idx<512; idx+=256){
    int b = idx>>5, c = (idx>>4)&1, t = idx&15;
    float acc = ldx(tc2b,c,bf);
    for(int o=0;o<32;o++){
      #pragma unroll
      for(int k=0;k<5;k++){
        int tt = t + k - 2;
        if(tt>=0 && tt<16) acc += t1[(b*32+o)*16+tt]*ldx(tc2w,(c*32+o)*5+k,bf);
      }
    }
    td[(b*2+c)*16+t] = acc;
  }
  __syncthreads();
  {
    int b = f>>4;
    float tdx = td[(b*2+0)*16+(f&15)], tdy = td[(b*2+1)*16+(f&15)];
    float cx2 = fminf(fmaxf(sxs[f] + 0.12f*tanhf(tdx), 0.f), 1.f);
    float cy2 = fminf(fmaxf(sys[f] + 0.12f*tanhf(tdy), 0.f), 1.f);
    const float ms = 1.0f/14.0f;
    float w  = fminf(fmaxf(ldx(fbw,0,bf), ms), 1.f);
    float ht = fminf(fmaxf(ldx(fbw,1,bf), ms), 1.f);
    float x1 = fminf(fmaxf(cx2 - 0.5f*w , 0.f), 1.f);
    float y1 = fminf(fmaxf(cy2 - 0.5f*ht, 0.f), 1.f);
    float x2 = fminf(fmaxf(cx2 + 0.5f*w , 0.f), 1.f);
    float y2 = fminf(fmaxf(cy2 + 0.5f*ht, 0.f), 1.f);
    x2 = fminf(fmaxf(fmaxf(x2, x1+ms), 0.f), 1.f);
    y2 = fminf(fmaxf(fmaxf(y2, y1+ms), 0.f), 1.f);
    if(bf){
      __hip_bfloat16* ob = (__hip_bfloat16*)out;
      ob[f*4+0]=__float2bfloat16(x1);
      ob[f*4+1]=__float2bfloat16(y1);
      ob[f*4+2]=__float2bfloat16(x2);
      ob[f*4+3]=__float2bfloat16(y2);
    } else {
      float* of = (float*)out;
      of[f*4+0]=x1; of[f*4+1]=y1; of[f*4+2]=x2; of[f*4+3]=y2;
    }
  }
}

extern "C" void kernel_launch(void* const* d_in, const int* in_sizes, int n_in,
                              void* d_out, int out_size, void* d_ws, size_t ws_size,
                              hipStream_t stream){
  (void)in_sizes; (void)n_in; (void)out_size; (void)ws_size;
  const void* tok   = d_in[0];
  const void* fbw   = d_in[2];
  const void* lnw   = d_in[3];   // dtype flag source (all-ones)
  const void* lnb   = d_in[4];
  const void* query = d_in[5];
  const void* wproj = d_in[6];
  const void* bproj = d_in[7];
  const void* outw  = d_in[8];
  const void* outb  = d_in[9];
  const void* anw   = d_in[10];
  const void* anb   = d_in[11];
  const void* objw  = d_in[12];
  const void* objb  = d_in[13];
  const void* temp  = d_in[14];
  const void* r1w   = d_in[15];
  const void* r1b   = d_in[16];
  const void* r2w   = d_in[17];
  const void* r2b   = d_in[18];
  const void* r3w   = d_in[19];
  const void* r3b   = d_in[20];
  const void* tc1w  = d_in[21];
  const void* tc1b  = d_in[22];
  const void* tc2w  = d_in[23];
  const void* tc2b  = d_in[24];

  float* ws    = (float*)d_ws;
  float* qh    = ws;
  float* wkraw = ws + 768;
  float* wf    = wkraw + 3072;
  float* s12   = wf + 3840;
  float* scores= s12 + 16;
  float* objv  = scores + 200704;
  float* meanv = objv + 50176;
  float* rstdv = meanv + 50176;
  float* cterm = rstdv + 50176;
  float* xbar  = cterm + 1024;
  float* ctx   = xbar + 786432;
  float* ppre  = ctx + 196608;
  float* pl    = ppre + 196608;
  float* h1    = pl + 393216;
  float* h2    = h1 + 65536;
  float* cxy   = h2 + 32768;

  hipLaunchKernelGGL(k_qh,    dim3(192),  dim3(256), 0, stream, query, wproj, bproj, lnw, qh);
  hipLaunchKernelGGL(k_wkeff, dim3(12),   dim3(256), 0, stream, wproj, qh, lnw, objw, wkraw, wf);
  hipLaunchKernelGGL(k_consts,dim3(1),    dim3(256), 0, stream, wf, wkraw, lnb, objw, lnw, s12);
  hipLaunchKernelGGL(k_pass1, dim3(3136), dim3(256), 0, stream, tok, wf, s12, objb, lnw, scores, objv, meanv, rstdv);
  hipLaunchKernelGGL(k_soft,  dim3(256),  dim3(256), 0, stream, rstdv, meanv, scores, cterm);
  hipLaunchKernelGGL(k_xbar,  dim3(256),  dim3(256), 0, stream, tok, scores, cterm, lnw, lnb, xbar);
  hipLaunchKernelGGL((k_dgemm<768,768,0,1,1536>), dim3(12,64), dim3(256), 0, stream, xbar, wproj, bproj, lnw, ctx);
  hipLaunchKernelGGL((k_dgemm<768,768,0,0,0>),    dim3(12,64), dim3(256), 0, stream, ctx, outw, outb, lnw, ppre);
  hipLaunchKernelGGL(k_lnan,  dim3(64),   dim3(256), 0, stream, ppre, anw, anb, lnw, pl);
  hipLaunchKernelGGL(k_obj,   dim3(256),  dim3(256), 0, stream, tok, objv, meanv, rstdv, temp, lnw, lnb, pl, cxy);
  hipLaunchKernelGGL((k_dgemm<256,1536,1,0,0>), dim3(4,64), dim3(256), 0, stream, pl, r1w, r1b, lnw, h1);
  hipLaunchKernelGGL((k_dgemm<128,256,1,0,0>),  dim3(2,64), dim3(256), 0, stream, h1, r2w, r2b, lnw, h2);
  hipLaunchKernelGGL(k_final, dim3(1),    dim3(256), 0, stream, h2, r3w, r3b, cxy, tc1w, tc1b, tc2w, tc2b, fbw, lnw, (void*)d_out);
}

// Round 5
// 535.225 us; speedup vs baseline: 1.2851x; 1.2851x over previous
//
#include <hip/hip_runtime.h>
#include <hip/hip_bf16.h>
#include <math.h>

#define SS 196
#define DD 768

__device__ __forceinline__ float b2f(ushort u){
  union { unsigned int i; float f; } v; v.i = ((unsigned int)u) << 16; return v.f;
}
__device__ __forceinline__ bool bfmode(const void* lnw){
  return ((const ushort*)lnw)[0] != 0;   // ln_w[0]==1.0: fp32 low half 0x0000, bf16 0x3F80
}
__device__ __forceinline__ float ldx(const void* p, size_t i, bool bf){
  return bf ? b2f(((const ushort*)p)[i]) : ((const float*)p)[i];
}
__device__ __forceinline__ float gelu_f(float x){
  return 0.5f * x * (1.0f + erff(x * 0.70710678118654752f));
}
__device__ __forceinline__ float wredsum(float v){
  #pragma unroll
  for(int o=32;o;o>>=1) v += __shfl_xor(v,o,64);
  return v;
}
__device__ __forceinline__ float wredmax(float v){
  #pragma unroll
  for(int o=32;o;o>>=1) v = fmaxf(v, __shfl_xor(v,o,64));
  return v;
}

__global__ __launch_bounds__(256) void k_qh(const void* __restrict__ q,
                                            const void* __restrict__ wq,
                                            const void* __restrict__ bq,
                                            const void* __restrict__ flagp,
                                            float* __restrict__ qh){
  bool bf = bfmode(flagp);
  int wv = threadIdx.x >> 6, lane = threadIdx.x & 63;
  int c = blockIdx.x * 4 + wv;
  float acc = 0.f;
  #pragma unroll
  for(int i=0;i<12;i++){ int d = lane + 64*i; acc += ldx(q,d,bf) * ldx(wq,(size_t)c*DD+d,bf); }
  acc = wredsum(acc);
  if(lane==0) qh[c] = acc + ldx(bq,c,bf);
}

__global__ __launch_bounds__(256) void k_wkeff(const void* __restrict__ wproj,
                                               const float* __restrict__ qh,
                                               const void* __restrict__ lnw,
                                               const void* __restrict__ objw,
                                               float* __restrict__ wkraw,
                                               float* __restrict__ wf){
  bool bf = bfmode(lnw);
  int idx = blockIdx.x*256 + threadIdx.x;
  int h = idx / DD, d = idx - h*DD;
  size_t base = ((size_t)(DD + h*192))*DD + d;
  const float* qp = qh + h*192;
  float acc = 0.f;
  #pragma unroll 8
  for(int j=0;j<192;j++) acc += qp[j] * ldx(wproj, base + (size_t)j*DD, bf);
  wkraw[idx] = acc;
  float w = ldx(lnw,d,bf);
  wf[idx] = w * acc;
  if(h==0) wf[4*DD + d] = w * ldx(objw,d,bf);
}

__global__ __launch_bounds__(256) void k_consts(const float* __restrict__ wf,
                                                const float* __restrict__ wkraw,
                                                const void* __restrict__ lnb,
                                                const void* __restrict__ objw,
                                                const void* __restrict__ flagp,
                                                float* __restrict__ s12){
  bool bf = bfmode(flagp);
  int wv = threadIdx.x >> 6, lane = threadIdx.x & 63;
  for(int r = wv; r < 10; r += 4){
    float acc = 0.f;
    #pragma unroll
    for(int i=0;i<12;i++){
      int d = lane + 64*i;
      if(r < 5)      acc += wf[r*DD + d];
      else if(r < 9) acc += ldx(lnb,d,bf) * wkraw[(r-5)*DD + d];
      else           acc += ldx(lnb,d,bf) * ldx(objw,d,bf);
    }
    acc = wredsum(acc);
    if(lane==0) s12[r] = acc;
  }
}

__global__ __launch_bounds__(256) void k_pass1(const void* __restrict__ tok,
                                               const float* __restrict__ wf,
                                               const float* __restrict__ s12,
                                               const void* __restrict__ objb,
                                               const void* __restrict__ flagp,
                                               float* __restrict__ scores,
                                               float* __restrict__ objv,
                                               float* __restrict__ meanv,
                                               float* __restrict__ rstdv){
  __shared__ __align__(16) float swf[5*DD];
  __shared__ float ss12[10];
  for(int i=threadIdx.x;i<5*DD;i+=256) swf[i]=wf[i];
  if(threadIdx.x<10) ss12[threadIdx.x]=s12[threadIdx.x];
  __syncthreads();
  bool bf = bfmode(flagp);
  int wv = threadIdx.x >> 6, lane = threadIdx.x & 63;
  for(int it=0; it<4; it++){
    int tkn = blockIdx.x*16 + wv*4 + it;
    int f = tkn / SS, s = tkn - f*SS;
    float a0=0,a1=0,a2=0,a3=0,a4=0,sm=0,sq=0;
    if(bf){
      const ushort* x = (const ushort*)tok + (size_t)tkn * DD;
      #pragma unroll
      for(int i=0;i<3;i++){
        int d = 4*lane + 256*i;
        ushort4 u = *(const ushort4*)(x + d);
        float x0=b2f(u.x), x1=b2f(u.y), x2=b2f(u.z), x3=b2f(u.w);
        sm += (x0+x1)+(x2+x3); sq += (x0*x0+x1*x1)+(x2*x2+x3*x3);
        float4 w;
        w = *(const float4*)&swf[0*DD+d]; a0 += x0*w.x + x1*w.y + x2*w.z + x3*w.w;
        w = *(const float4*)&swf[1*DD+d]; a1 += x0*w.x + x1*w.y + x2*w.z + x3*w.w;
        w = *(const float4*)&swf[2*DD+d]; a2 += x0*w.x + x1*w.y + x2*w.z + x3*w.w;
        w = *(const float4*)&swf[3*DD+d]; a3 += x0*w.x + x1*w.y + x2*w.z + x3*w.w;
        w = *(const float4*)&swf[4*DD+d]; a4 += x0*w.x + x1*w.y + x2*w.z + x3*w.w;
      }
    } else {
      const float* x = (const float*)tok + (size_t)tkn * DD;
      #pragma unroll
      for(int i=0;i<3;i++){
        int d = 4*lane + 256*i;
        float4 u = *(const float4*)(x + d);
        sm += u.x+u.y+u.z+u.w;
        sq += u.x*u.x+u.y*u.y+u.z*u.z+u.w*u.w;
        float4 w;
        w = *(const float4*)&swf[0*DD+d]; a0 += u.x*w.x+u.y*w.y+u.z*w.z+u.w*w.w;
        w = *(const float4*)&swf[1*DD+d]; a1 += u.x*w.x+u.y*w.y+u.z*w.z+u.w*w.w;
        w = *(const float4*)&swf[2*DD+d]; a2 += u.x*w.x+u.y*w.y+u.z*w.z+u.w*w.w;
        w = *(const float4*)&swf[3*DD+d]; a3 += u.x*w.x+u.y*w.y+u.z*w.z+u.w*w.w;
        w = *(const float4*)&swf[4*DD+d]; a4 += u.x*w.x+u.y*w.y+u.z*w.z+u.w*w.w;
      }
    }
    sm=wredsum(sm); sq=wredsum(sq);
    a0=wredsum(a0); a1=wredsum(a1); a2=wredsum(a2); a3=wredsum(a3); a4=wredsum(a4);
    if(lane==0){
      const float invD = 1.0f/768.0f;
      float m = sm*invD;
      float var = sq*invD - m*m;
      float rstd = rsqrtf(var + 1e-5f);
      meanv[tkn]=m; rstdv[tkn]=rstd;
      const float sc = 0.07216878364870322f;
      scores[(f*4+0)*SS+s] = (rstd*(a0 - m*ss12[0]) + ss12[5]) * sc;
      scores[(f*4+1)*SS+s] = (rstd*(a1 - m*ss12[1]) + ss12[6]) * sc;
      scores[(f*4+2)*SS+s] = (rstd*(a2 - m*ss12[2]) + ss12[7]) * sc;
      scores[(f*4+3)*SS+s] = (rstd*(a3 - m*ss12[3]) + ss12[8]) * sc;
      objv[tkn] = rstd*(a4 - m*ss12[4]) + ss12[9] + ldx(objb,0,bf);
    }
  }
}

__global__ __launch_bounds__(256) void k_soft(const float* __restrict__ rstdv,
                                              const float* __restrict__ meanv,
                                              float* __restrict__ scores,
                                              float* __restrict__ cterm){
  int f = blockIdx.x;
  int h = threadIdx.x >> 6, lane = threadIdx.x & 63;
  float* sc = scores + (size_t)(f*4+h)*SS;
  const float* rs = rstdv + f*SS;
  const float* mv = meanv + f*SS;
  float v[4]; float mx = -1e30f;
  #pragma unroll
  for(int j=0;j<4;j++){ int s=lane+64*j; v[j] = (s<SS)? sc[s] : -1e30f; mx=fmaxf(mx,v[j]); }
  mx = wredmax(mx);
  float e[4], sum=0.f;
  #pragma unroll
  for(int j=0;j<4;j++){ int s=lane+64*j; e[j] = (s<SS)? expf(v[j]-mx) : 0.f; sum += e[j]; }
  sum = wredsum(sum);
  float inv = 1.0f/sum;
  float cp = 0.f;
  #pragma unroll
  for(int j=0;j<4;j++){
    int s=lane+64*j;
    if(s<SS){ float r=rs[s]; float a=e[j]*inv*r; sc[s]=a; cp += a*mv[s]; }
  }
  cp = wredsum(cp);
  if(lane==0) cterm[f*4+h] = cp;
}

__global__ __launch_bounds__(256) void k_xbar(const void* __restrict__ tok,
                                              const float* __restrict__ aw,
                                              const float* __restrict__ cterm,
                                              const void* __restrict__ lnw,
                                              const void* __restrict__ lnb,
                                              float* __restrict__ xbar){
  bool bf = bfmode(lnw);
  int f = blockIdx.x;
  __shared__ float a4[SS*4];
  for(int i=threadIdx.x;i<SS*4;i+=256){ int s=i>>2, h=i&3; a4[i]=aw[(size_t)(f*4+h)*SS+s]; }
  __syncthreads();
  float acc[3][4] = {};
  if(bf){
    const ushort* tf = (const ushort*)tok + (size_t)f*SS*DD;
    for(int s=0;s<SS;s++){
      float w0=a4[s*4+0], w1=a4[s*4+1], w2=a4[s*4+2], w3=a4[s*4+3];
      #pragma unroll
      for(int j=0;j<3;j++){
        float x = b2f(tf[(size_t)s*DD + threadIdx.x + 256*j]);
        acc[j][0]+=w0*x; acc[j][1]+=w1*x; acc[j][2]+=w2*x; acc[j][3]+=w3*x;
      }
    }
  } else {
    const float* tf = (const float*)tok + (size_t)f*SS*DD;
    for(int s=0;s<SS;s++){
      float w0=a4[s*4+0], w1=a4[s*4+1], w2=a4[s*4+2], w3=a4[s*4+3];
      #pragma unroll
      for(int j=0;j<3;j++){
        float x = tf[(size_t)s*DD + threadIdx.x + 256*j];
        acc[j][0]+=w0*x; acc[j][1]+=w1*x; acc[j][2]+=w2*x; acc[j][3]+=w3*x;
      }
    }
  }
  float c0=cterm[f*4+0], c1=cterm[f*4+1], c2=cterm[f*4+2], c3=cterm[f*4+3];
  #pragma unroll
  for(int j=0;j<3;j++){
    int d = threadIdx.x + 256*j;
    float w=ldx(lnw,d,bf), b=ldx(lnb,d,bf);
    xbar[((size_t)(f*4+0))*DD+d] = w*(acc[j][0]-c0)+b;
    xbar[((size_t)(f*4+1))*DD+d] = w*(acc[j][1]-c1)+b;
    xbar[((size_t)(f*4+2))*DD+d] = w*(acc[j][2]-c2)+b;
    xbar[((size_t)(f*4+3))*DD+d] = w*(acc[j][3]-c3)+b;
  }
}

// ---- LDS-tiled GEMM: C[256][N] = A[256][K] @ W[ROWOFF+n][K]^T + bias ------------
// Block 256 thr computes 32m x 64n tile; K staged in 32-chunks (A->[k][m], W->[k][n]
// in LDS, coalesced 16B global loads, next chunk prefetched during compute).
// grid (N/64, 256/32). CTX=1: A row for m, col block n0 is xbar[(m*4 + n0/192)*768].
template<int N, int K, int ACT, int CTX, int ROWOFF>
__global__ __launch_bounds__(256) void k_tgemm(const float* __restrict__ A,
                                               const void* __restrict__ W,
                                               const void* __restrict__ bias,
                                               const void* __restrict__ flagp,
                                               float* __restrict__ C){
  bool bf = bfmode(flagp);
  __shared__ float As[32][32];   // [k][m]
  __shared__ float Bs[32][64];   // [k][n]
  int tid = threadIdx.x;
  int n0 = blockIdx.x*64, m0 = blockIdx.y*32;
  int h  = n0 / 192;
  int am = tid>>3, ak = (tid&7)*4;   // A loader: row m0+am (32 rows), k ak..ak+3
  int bn = tid>>2, bk = (tid&3)*8;   // B loader: row n0+bn (64 rows), k bk..bk+7
  const float* ap = A + (CTX ? ((size_t)((m0+am)*4+h))*768 : (size_t)(m0+am)*K) + ak;
  const ushort* wpb = (const ushort*)W + (size_t)(ROWOFF+n0+bn)*K + bk;
  const float*  wpf = (const float*)W  + (size_t)(ROWOFF+n0+bn)*K + bk;
  int tx = tid&15, ty = tid>>4;      // compute: m=m0+ty*2+{0,1}, n=n0+tx*4+{0..3}
  float acc[2][4] = {};
  float4 av; float b8[8];
  // prologue load (chunk 0)
  av = *(const float4*)ap;
  if(bf){
    ushort4 w0 = *(const ushort4*)(wpb);
    ushort4 w1 = *(const ushort4*)(wpb+4);
    b8[0]=b2f(w0.x); b8[1]=b2f(w0.y); b8[2]=b2f(w0.z); b8[3]=b2f(w0.w);
    b8[4]=b2f(w1.x); b8[5]=b2f(w1.y); b8[6]=b2f(w1.z); b8[7]=b2f(w1.w);
  } else {
    float4 w0 = *(const float4*)(wpf);
    float4 w1 = *(const float4*)(wpf+4);
    b8[0]=w0.x; b8[1]=w0.y; b8[2]=w0.z; b8[3]=w0.w;
    b8[4]=w1.x; b8[5]=w1.y; b8[6]=w1.z; b8[7]=w1.w;
  }
  for(int k0=0; k0<K; k0+=32){
    As[ak+0][am]=av.x; As[ak+1][am]=av.y; As[ak+2][am]=av.z; As[ak+3][am]=av.w;
    #pragma unroll
    for(int j=0;j<8;j++) Bs[bk+j][bn]=b8[j];
    __syncthreads();
    float4 av2; float b82[8];
    if(k0+32 < K){
      av2 = *(const float4*)(ap + k0 + 32);
      if(bf){
        ushort4 w0 = *(const ushort4*)(wpb + k0 + 32);
        ushort4 w1 = *(const ushort4*)(wpb + k0 + 36);
        b82[0]=b2f(w0.x); b82[1]=b2f(w0.y); b82[2]=b2f(w0.z); b82[3]=b2f(w0.w);
        b82[4]=b2f(w1.x); b82[5]=b2f(w1.y); b82[6]=b2f(w1.z); b82[7]=b2f(w1.w);
      } else {
        float4 w0 = *(const float4*)(wpf + k0 + 32);
        float4 w1 = *(const float4*)(wpf + k0 + 36);
        b82[0]=w0.x; b82[1]=w0.y; b82[2]=w0.z; b82[3]=w0.w;
        b82[4]=w1.x; b82[5]=w1.y; b82[6]=w1.z; b82[7]=w1.w;
      }
    }
    #pragma unroll
    for(int k=0;k<32;k++){
      float2 a = *(const float2*)&As[k][ty*2];
      float4 b = *(const float4*)&Bs[k][tx*4];
      acc[0][0]+=a.x*b.x; acc[0][1]+=a.x*b.y; acc[0][2]+=a.x*b.z; acc[0][3]+=a.x*b.w;
      acc[1][0]+=a.y*b.x; acc[1][1]+=a.y*b.y; acc[1][2]+=a.y*b.z; acc[1][3]+=a.y*b.w;
    }
    __syncthreads();
    av = av2;
    #pragma unroll
    for(int j=0;j<8;j++) b8[j]=b82[j];
  }
  int n = n0 + tx*4;
  float bv0=ldx(bias,ROWOFF+n,bf),   bv1=ldx(bias,ROWOFF+n+1,bf),
        bv2=ldx(bias,ROWOFF+n+2,bf), bv3=ldx(bias,ROWOFF+n+3,bf);
  #pragma unroll
  for(int i=0;i<2;i++){
    int m = m0 + ty*2 + i;
    float4 o;
    o.x=acc[i][0]+bv0; o.y=acc[i][1]+bv1; o.z=acc[i][2]+bv2; o.w=acc[i][3]+bv3;
    if(ACT){ o.x=gelu_f(o.x); o.y=gelu_f(o.y); o.z=gelu_f(o.z); o.w=gelu_f(o.w); }
    *(float4*)&C[(size_t)m*N + n] = o;
  }
}

__global__ __launch_bounds__(256) void k_lnan(const float* __restrict__ X,
                                              const void* __restrict__ anw,
                                              const void* __restrict__ anb,
                                              const void* __restrict__ flagp,
                                              float* __restrict__ pl){
  bool bf = bfmode(flagp);
  int wv = threadIdx.x >> 6, lane = threadIdx.x & 63;
  int f = blockIdx.x*4 + wv;
  const float* x = X + (size_t)f*DD;
  float v[12]; float sm=0, sq=0;
  #pragma unroll
  for(int i=0;i<12;i++){ v[i]=x[lane+64*i]; sm+=v[i]; sq+=v[i]*v[i]; }
  sm=wredsum(sm); sq=wredsum(sq);
  float m = sm*(1.0f/768.0f);
  float rstd = rsqrtf(sq*(1.0f/768.0f) - m*m + 1e-5f);
  #pragma unroll
  for(int i=0;i<12;i++){
    int d = lane+64*i;
    pl[(size_t)f*1536 + d] = (v[i]-m)*rstd*ldx(anw,d,bf) + ldx(anb,d,bf);
  }
}

__global__ __launch_bounds__(256) void k_obj(const void* __restrict__ tok,
                                             const float* __restrict__ objv,
                                             const float* __restrict__ meanv,
                                             const float* __restrict__ rstdv,
                                             const void* __restrict__ temp,
                                             const void* __restrict__ lnw,
                                             const void* __restrict__ lnb,
                                             float* __restrict__ pl,
                                             float* __restrict__ cxy){
  bool bf = bfmode(lnw);
  int f = blockIdx.x;
  int tid = threadIdx.x;
  __shared__ float G[196];
  __shared__ float up[3136];
  __shared__ int   i0a[56], i1a[56];
  __shared__ float w0a[56], w1a[56];
  __shared__ float redm[4], reds[4], redx[4], redy[4];
  __shared__ int   sidx[9];
  __shared__ float rj[9], rmj[9];
  if(tid<196) G[tid] = objv[(size_t)f*SS + tid];
  if(tid<56){
    float src = fmaxf((tid+0.5f)*0.25f - 0.5f, 0.0f);
    int i0 = min((int)floorf(src), 13);
    i0a[tid]=i0; i1a[tid]=min(i0+1,13);
    float w1 = src - (float)i0;
    w1a[tid]=w1; w0a[tid]=1.0f-w1;
  }
  __syncthreads();
  float lmax = -1e30f;
  for(int i=tid;i<3136;i+=256){
    int u=i/56, v=i-u*56;
    float val = w0a[u]*(w0a[v]*G[i0a[u]*14+i0a[v]] + w1a[v]*G[i0a[u]*14+i1a[v]])
              + w1a[u]*(w0a[v]*G[i1a[u]*14+i0a[v]] + w1a[v]*G[i1a[u]*14+i1a[v]]);
    up[i]=val; lmax=fmaxf(lmax,val);
  }
  lmax = wredmax(lmax);
  if((tid&63)==0) redm[tid>>6]=lmax;
  __syncthreads();
  float mx = fmaxf(fmaxf(redm[0],redm[1]), fmaxf(redm[2],redm[3]));
  float t = fmaxf(ldx(temp,0,bf), 1.0f);
  float se=0, sx=0, sy=0;
  for(int i=tid;i<3136;i+=256){
    int u=i/56, v=i-u*56;
    float e = expf((up[i]-mx)*t);
    se += e;
    sx += e * ((v+0.5f)*(1.0f/56.0f));
    sy += e * ((u+0.5f)*(1.0f/56.0f));
  }
  se=wredsum(se); sx=wredsum(sx); sy=wredsum(sy);
  if((tid&63)==0){ reds[tid>>6]=se; redx[tid>>6]=sx; redy[tid>>6]=sy; }
  __syncthreads();
  se = reds[0]+reds[1]+reds[2]+reds[3];
  sx = redx[0]+redx[1]+redx[2]+redx[3];
  sy = redy[0]+redy[1]+redy[2]+redy[3];
  float cx0 = sx/se, cy0 = sy/se;
  if(tid==0){ cxy[f*2]=cx0; cxy[f*2+1]=cy0; }
  float vx = fminf(fmaxf(cx0*14.0f,0.0f),13.0f); int cxg=(int)vx;
  float vy = fminf(fmaxf(cy0*14.0f,0.0f),13.0f); int cyg=(int)vy;
  if(tid<9){
    int dy = tid/3 - 1, dx = tid%3 - 1;
    int gy = min(max(cyg+dy,0),13), gx = min(max(cxg+dx,0),13);
    int s = gy*14+gx;
    sidx[tid]=s;
    float r = rstdv[(size_t)f*SS+s];
    rj[tid]=r; rmj[tid]=r*meanv[(size_t)f*SS+s];
  }
  __syncthreads();
  float offc = 0.f;
  #pragma unroll
  for(int j=0;j<9;j++) offc += rmj[j];
  for(int d=tid; d<DD; d+=256){
    float acc = 0.f;
    #pragma unroll
    for(int j=0;j<9;j++) acc += rj[j]*ldx(tok, (size_t)f*SS*DD + (size_t)sidx[j]*DD + d, bf);
    pl[(size_t)f*1536 + DD + d] = ldx(lnw,d,bf)*((acc-offc)*(1.0f/9.0f)) + ldx(lnb,d,bf);
  }
}

__global__ __launch_bounds__(256) void k_final(const float* __restrict__ h2,
                                               const void* __restrict__ r3w,
                                               const void* __restrict__ r3b,
                                               const float* __restrict__ cxy,
                                               const void* __restrict__ tc1w,
                                               const void* __restrict__ tc1b,
                                               const void* __restrict__ tc2w,
                                               const void* __restrict__ tc2b,
                                               const void* __restrict__ fbw,
                                               const void* __restrict__ flagp,
                                               void* __restrict__ out){
  bool bf = bfmode(flagp);
  __shared__ float sxs[256], sys[256];
  __shared__ float t1[16*32*16];
  __shared__ float td[16*2*16];
  int f = threadIdx.x;
  float a0=0.f, a1=0.f;
  const float* hh = h2 + (size_t)f*128;
  for(int k=0;k<128;k++){ float x=hh[k]; a0 += x*ldx(r3w,k,bf); a1 += x*ldx(r3w,128+k,bf); }
  a0 += ldx(r3b,0,bf); a1 += ldx(r3b,1,bf);
  float cx1 = fminf(fmaxf(cxy[f*2]   + 0.3f*tanhf(a0), 0.f), 1.f);
  float cy1 = fminf(fmaxf(cxy[f*2+1] + 0.3f*tanhf(a1), 0.f), 1.f);
  sxs[f]=cx1; sys[f]=cy1;
  __syncthreads();
  for(int idx=f; idx<8192; idx+=256){
    int b = idx>>9, o = (idx>>4)&31, t = idx&15;
    float acc = ldx(tc1b,o,bf);
    #pragma unroll
    for(int k=0;k<5;k++){
      int tt = t + k - 2;
      if(tt>=0 && tt<16)
        acc += sxs[b*16+tt]*ldx(tc1w,o*10 + k,bf) + sys[b*16+tt]*ldx(tc1w,o*10 + 5 + k,bf);
    }
    t1[idx] = gelu_f(acc);
  }
  __syncthreads();
  for(int idx=f; idx<512; idx+=256){
    int b = idx>>5, c = (idx>>4)&1, t = idx&15;
    float acc = ldx(tc2b,c,bf);
    for(int o=0;o<32;o++){
      #pragma unroll
      for(int k=0;k<5;k++){
        int tt = t + k - 2;
        if(tt>=0 && tt<16) acc += t1[(b*32+o)*16+tt]*ldx(tc2w,(c*32+o)*5+k,bf);
      }
    }
    td[(b*2+c)*16+t] = acc;
  }
  __syncthreads();
  {
    int b = f>>4;
    float tdx = td[(b*2+0)*16+(f&15)], tdy = td[(b*2+1)*16+(f&15)];
    float cx2 = fminf(fmaxf(sxs[f] + 0.12f*tanhf(tdx), 0.f), 1.f);
    float cy2 = fminf(fmaxf(sys[f] + 0.12f*tanhf(tdy), 0.f), 1.f);
    const float ms = 1.0f/14.0f;
    float w  = fminf(fmaxf(ldx(fbw,0,bf), ms), 1.f);
    float ht = fminf(fmaxf(ldx(fbw,1,bf), ms), 1.f);
    float x1 = fminf(fmaxf(cx2 - 0.5f*w , 0.f), 1.f);
    float y1 = fminf(fmaxf(cy2 - 0.5f*ht, 0.f), 1.f);
    float x2 = fminf(fmaxf(cx2 + 0.5f*w , 0.f), 1.f);
    float y2 = fminf(fmaxf(cy2 + 0.5f*ht, 0.f), 1.f);
    x2 = fminf(fmaxf(fmaxf(x2, x1+ms), 0.f), 1.f);
    y2 = fminf(fmaxf(fmaxf(y2, y1+ms), 0.f), 1.f);
    if(bf){
      __hip_bfloat16* ob = (__hip_bfloat16*)out;
      ob[f*4+0]=__float2bfloat16(x1);
      ob[f*4+1]=__float2bfloat16(y1);
      ob[f*4+2]=__float2bfloat16(x2);
      ob[f*4+3]=__float2bfloat16(y2);
    } else {
      float* of = (float*)out;
      of[f*4+0]=x1; of[f*4+1]=y1; of[f*4+2]=x2; of[f*4+3]=y2;
    }
  }
}

extern "C" void kernel_launch(void* const* d_in, const int* in_sizes, int n_in,
                              void* d_out, int out_size, void* d_ws, size_t ws_size,
                              hipStream_t stream){
  (void)in_sizes; (void)n_in; (void)out_size; (void)ws_size;
  const void* tok   = d_in[0];
  const void* fbw   = d_in[2];
  const void* lnw   = d_in[3];   // dtype flag source (all-ones)
  const void* lnb   = d_in[4];
  const void* query = d_in[5];
  const void* wproj = d_in[6];
  const void* bproj = d_in[7];
  const void* outw  = d_in[8];
  const void* outb  = d_in[9];
  const void* anw   = d_in[10];
  const void* anb   = d_in[11];
  const void* objw  = d_in[12];
  const void* objb  = d_in[13];
  const void* temp  = d_in[14];
  const void* r1w   = d_in[15];
  const void* r1b   = d_in[16];
  const void* r2w   = d_in[17];
  const void* r2b   = d_in[18];
  const void* r3w   = d_in[19];
  const void* r3b   = d_in[20];
  const void* tc1w  = d_in[21];
  const void* tc1b  = d_in[22];
  const void* tc2w  = d_in[23];
  const void* tc2b  = d_in[24];

  float* ws    = (float*)d_ws;
  float* qh    = ws;
  float* wkraw = ws + 768;
  float* wf    = wkraw + 3072;
  float* s12   = wf + 3840;
  float* scores= s12 + 16;
  float* objv  = scores + 200704;
  float* meanv = objv + 50176;
  float* rstdv = meanv + 50176;
  float* cterm = rstdv + 50176;
  float* xbar  = cterm + 1024;
  float* ctx   = xbar + 786432;
  float* ppre  = ctx + 196608;
  float* pl    = ppre + 196608;
  float* h1    = pl + 393216;
  float* h2    = h1 + 65536;
  float* cxy   = h2 + 32768;

  hipLaunchKernelGGL(k_qh,    dim3(192),  dim3(256), 0, stream, query, wproj, bproj, lnw, qh);
  hipLaunchKernelGGL(k_wkeff, dim3(12),   dim3(256), 0, stream, wproj, qh, lnw, objw, wkraw, wf);
  hipLaunchKernelGGL(k_consts,dim3(1),    dim3(256), 0, stream, wf, wkraw, lnb, objw, lnw, s12);
  hipLaunchKernelGGL(k_pass1, dim3(3136), dim3(256), 0, stream, tok, wf, s12, objb, lnw, scores, objv, meanv, rstdv);
  hipLaunchKernelGGL(k_soft,  dim3(256),  dim3(256), 0, stream, rstdv, meanv, scores, cterm);
  hipLaunchKernelGGL(k_xbar,  dim3(256),  dim3(256), 0, stream, tok, scores, cterm, lnw, lnb, xbar);
  hipLaunchKernelGGL((k_tgemm<768,768,0,1,1536>), dim3(12,8), dim3(256), 0, stream, xbar, wproj, bproj, lnw, ctx);
  hipLaunchKernelGGL((k_tgemm<768,768,0,0,0>),    dim3(12,8), dim3(256), 0, stream, ctx, outw, outb, lnw, ppre);
  hipLaunchKernelGGL(k_lnan,  dim3(64),   dim3(256), 0, stream, ppre, anw, anb, lnw, pl);
  hipLaunchKernelGGL(k_obj,   dim3(256),  dim3(256), 0, stream, tok, objv, meanv, rstdv, temp, lnw, lnb, pl, cxy);
  hipLaunchKernelGGL((k_tgemm<256,1536,1,0,0>), dim3(4,8), dim3(256), 0, stream, pl, r1w, r1b, lnw, h1);
  hipLaunchKernelGGL((k_tgemm<128,256,1,0,0>),  dim3(2,8), dim3(256), 0, stream, h1, r2w, r2b, lnw, h2);
  hipLaunchKernelGGL(k_final, dim3(1),    dim3(256), 0, stream, h2, r3w, r3b, cxy, tc1w, tc1b, tc2w, tc2b, fbw, lnw, (void*)d_out);
}